// Round 10
// baseline (331.531 us; speedup 1.0000x reference)
//
#include <hip/hip_runtime.h>
#include <hip/hip_fp8.h>
#include <math.h>

typedef __attribute__((ext_vector_type(2))) float fv2;

#if defined(__has_builtin)
#  if __has_builtin(__builtin_amdgcn_cvt_pk_f32_fp8) && \
      __has_builtin(__builtin_amdgcn_cvt_pk_fp8_f32)
#    define PE_HAVE_FP8_BUILTINS 1
#  endif
#endif

#define MAX_NBP 512          // max c-buckets for binned path
#define NPB 256              // nodes per bucket
#define NPB_SHIFT 8
#define B2_EPT 16            // edges per thread in count/binify
#define B2_CHUNK (B2_EPT * 256)   // 4096 edges per block
#define CPB 4                // chunks per bucket in dotred

// pack 4 floats -> 4 fp8 e4m3 bytes in one uint32
__device__ __forceinline__ unsigned pack4_fp8(float a, float b, float c, float d) {
#ifdef PE_HAVE_FP8_BUILTINS
    int w = 0;
    w = __builtin_amdgcn_cvt_pk_fp8_f32(a, b, w, false);  // bytes 0,1
    w = __builtin_amdgcn_cvt_pk_fp8_f32(c, d, w, true);   // bytes 2,3
    return (unsigned)w;
#else
    unsigned r = 0;
    r |= (unsigned)__hip_fp8_e4m3(a).__x;
    r |= (unsigned)__hip_fp8_e4m3(b).__x << 8;
    r |= (unsigned)__hip_fp8_e4m3(c).__x << 16;
    r |= (unsigned)__hip_fp8_e4m3(d).__x << 24;
    return r;
#endif
}

__device__ __forceinline__ float dot4w_fp8(unsigned qa, unsigned ka, float acc) {
#ifdef PE_HAVE_FP8_BUILTINS
    fv2 q0 = __builtin_amdgcn_cvt_pk_f32_fp8((int)qa, false);
    fv2 q1 = __builtin_amdgcn_cvt_pk_f32_fp8((int)qa, true);
    fv2 k0 = __builtin_amdgcn_cvt_pk_f32_fp8((int)ka, false);
    fv2 k1 = __builtin_amdgcn_cvt_pk_f32_fp8((int)ka, true);
    acc = fmaf(q0.x, k0.x, acc);
    acc = fmaf(q0.y, k0.y, acc);
    acc = fmaf(q1.x, k1.x, acc);
    acc = fmaf(q1.y, k1.y, acc);
    return acc;
#else
#pragma unroll
    for (int j = 0; j < 4; ++j) {
        __hip_fp8_e4m3 qv, kv;
        qv.__x = (qa >> (8 * j)) & 0xff;
        kv.__x = (ka >> (8 * j)) & 0xff;
        acc = fmaf((float)qv, (float)kv, acc);
    }
    return acc;
#endif
}

__device__ __forceinline__ float dot16_fp8(const uint4& q, const uint4& k) {
    float d = 0.0f;
    d = dot4w_fp8(q.x, k.x, d);
    d = dot4w_fp8(q.y, k.y, d);
    d = dot4w_fp8(q.z, k.z, d);
    d = dot4w_fp8(q.w, k.w, d);
    return d;
}

__device__ __forceinline__ float red4(float d) {
    d += __shfl_xor(d, 1, 64);
    d += __shfl_xor(d, 2, 64);
    return d;
}

// Pass 0 (merged): blocks [0, nblk) do the per-chunk bucket histogram
// (dispatched FIRST: slower blocks start earliest, smaller makespan);
// blocks [nblk, nblk+nconv) do fp32->fp8 conversion + zeroing.
// cnt layout is [blk][bin] (row stride nbp) -> coalesced row writes.
__global__ __launch_bounds__(256) void pe_convcount_kernel(
    const float* __restrict__ Q,
    const float* __restrict__ K,
    unsigned* __restrict__ Qq,   // row = 16 uints = 64 fp8
    unsigned* __restrict__ Kq,
    float* __restrict__ node_sum,
    float* __restrict__ out,
    unsigned* __restrict__ bucket_done,
    const int* __restrict__ c,
    unsigned* __restrict__ cnt,       // [nblk][nbp]
    int n4, int num_nodes, int num_graphs, int num_edges,
    int nbp, int nblk) {
    __shared__ unsigned h[MAX_NBP];
    const int tid = threadIdx.x;

    if (blockIdx.x >= nblk) {
        const int i = (blockIdx.x - nblk) * 256 + tid;
        if (i < num_nodes) node_sum[i] = 0.0f;
        if (i < num_graphs) out[i] = 0.0f;
        if (i < MAX_NBP) bucket_done[i] = 0u;
        if (i >= n4) return;
        const float4 q = ((const float4*)Q)[i];
        const float4 k = ((const float4*)K)[i];
        Qq[i] = pack4_fp8(q.x, q.y, q.z, q.w);
        Kq[i] = pack4_fp8(k.x, k.y, k.z, k.w);
        return;
    }

    // ---- count branch ----
    const int blk = blockIdx.x;
    for (int b = tid; b < MAX_NBP; b += 256) h[b] = 0u;
    __syncthreads();

    const int estart = blk * B2_CHUNK;
    const int ecount = min(B2_CHUNK, num_edges - estart);
    const int n4e = ecount >> 2;
    const int4* c4 = (const int4*)(c + estart);
    for (int k = tid; k < n4e; k += 256) {
        const int4 v = c4[k];
        atomicAdd(&h[v.x >> NPB_SHIFT], 1u);
        atomicAdd(&h[v.y >> NPB_SHIFT], 1u);
        atomicAdd(&h[v.z >> NPB_SHIFT], 1u);
        atomicAdd(&h[v.w >> NPB_SHIFT], 1u);
    }
    for (int e = (n4e << 2) + tid; e < ecount; e += 256)
        atomicAdd(&h[c[estart + e] >> NPB_SHIFT], 1u);
    __syncthreads();

    // coalesced row write (includes zero pad columns)
    for (int b = tid; b < nbp; b += 256)
        cnt[(size_t)blk * nbp + b] = h[b];
}

// Per-bin exclusive scan over blocks, cnt layout [blk][bin], in place.
// One block per 16-bin tile; each thread consumes a FULL 64B line (16 u32).
__global__ __launch_bounds__(256) void pe_matscan_kernel(
    unsigned* __restrict__ cnt,       // [nblk][nbp]
    unsigned* __restrict__ bin_cnt,
    int nblk, int nbp) {
    __shared__ unsigned wsum[4][16];
    const int t = threadIdx.x;
    const int lane = t & 63;
    const int w = t >> 6;
    const int col0 = blockIdx.x * 16;

    unsigned carry[16];
#pragma unroll
    for (int i = 0; i < 16; ++i) carry[i] = 0u;

    for (int t0 = 0; t0 < nblk; t0 += 256) {
        const int blk = t0 + t;
        unsigned v[16], orig[16];
        if (blk < nblk) {
            const uint4* p = (const uint4*)(cnt + (size_t)blk * nbp + col0);
            const uint4 a = p[0], b = p[1], cc = p[2], dd = p[3];
            v[0]=a.x;  v[1]=a.y;  v[2]=a.z;  v[3]=a.w;
            v[4]=b.x;  v[5]=b.y;  v[6]=b.z;  v[7]=b.w;
            v[8]=cc.x; v[9]=cc.y; v[10]=cc.z; v[11]=cc.w;
            v[12]=dd.x; v[13]=dd.y; v[14]=dd.z; v[15]=dd.w;
        } else {
#pragma unroll
            for (int i = 0; i < 16; ++i) v[i] = 0u;
        }
#pragma unroll
        for (int i = 0; i < 16; ++i) orig[i] = v[i];

        // wave-level inclusive scan (vector of 16)
#pragma unroll
        for (int off = 1; off < 64; off <<= 1) {
            unsigned nv[16];
#pragma unroll
            for (int i = 0; i < 16; ++i) nv[i] = __shfl_up(v[i], off, 64);
            if (lane >= off) {
#pragma unroll
                for (int i = 0; i < 16; ++i) v[i] += nv[i];
            }
        }
        if (lane == 63) {
#pragma unroll
            for (int i = 0; i < 16; ++i) wsum[w][i] = v[i];
        }
        __syncthreads();

        unsigned woff[16];
#pragma unroll
        for (int i = 0; i < 16; ++i) woff[i] = 0u;
        for (int ww = 0; ww < w; ++ww)
#pragma unroll
            for (int i = 0; i < 16; ++i) woff[i] += wsum[ww][i];

        if (blk < nblk) {
            uint4 o[4];
            unsigned e[16];
#pragma unroll
            for (int i = 0; i < 16; ++i) e[i] = carry[i] + woff[i] + v[i] - orig[i];
            o[0] = make_uint4(e[0], e[1], e[2], e[3]);
            o[1] = make_uint4(e[4], e[5], e[6], e[7]);
            o[2] = make_uint4(e[8], e[9], e[10], e[11]);
            o[3] = make_uint4(e[12], e[13], e[14], e[15]);
            uint4* p = (uint4*)(cnt + (size_t)blk * nbp + col0);
            p[0] = o[0]; p[1] = o[1]; p[2] = o[2]; p[3] = o[3];
        }

#pragma unroll
        for (int i = 0; i < 16; ++i)
            carry[i] += wsum[0][i] + wsum[1][i] + wsum[2][i] + wsum[3][i];
        __syncthreads();   // protect wsum before next iteration
    }

    if (t == 0) {
#pragma unroll
        for (int i = 0; i < 16; ++i) bin_cnt[col0 + i] = carry[i];
    }
}

// Binify: deterministic scatter with LDS reorder (coarse buckets).
// The global bin_base is computed LOCALLY (256-wide pair scan of bin_cnt,
// ~1.5 KB read, free) -- the standalone scan kernel is eliminated.
__global__ __launch_bounds__(256) void pe_binify_kernel(
    const int* __restrict__ c,
    const int* __restrict__ u,
    const unsigned* __restrict__ cnt,        // scanned, [nblk][nbp]
    const unsigned* __restrict__ bin_cnt,
    unsigned* __restrict__ recs,
    int num_edges, int nb, int nbp, int nblk) {
    __shared__ unsigned rank[MAX_NBP];        // 2 KB
    __shared__ unsigned lstart[MAX_NBP];      // 2 KB
    __shared__ unsigned basesh[MAX_NBP];      // 2 KB
    __shared__ unsigned srec[B2_CHUNK];       // 16 KB reordered records
    __shared__ unsigned short sbuk[B2_CHUNK]; // 8 KB bucket per slot
    __shared__ unsigned sc[256];              // 1 KB scan scratch
    __shared__ unsigned wtot[4];

    const int tid = threadIdx.x;
    const int blk = blockIdx.x;
    const int estart = blk * B2_CHUNK;
    const int ecount = min(B2_CHUNK, num_edges - estart);

    for (int b = tid; b < MAX_NBP; b += 256) rank[b] = 0u;

    // local exclusive scan of bin_cnt -> per-block global bases
    {
        const int i0 = 2 * tid, i1 = 2 * tid + 1;
        const unsigned v0 = (i0 < nb) ? bin_cnt[i0] : 0u;
        const unsigned v1 = (i1 < nb) ? bin_cnt[i1] : 0u;
        const unsigned p = v0 + v1;
        sc[tid] = p;
        __syncthreads();
        for (int off = 1; off < 256; off <<= 1) {
            const unsigned mine = sc[tid];
            const unsigned add = (tid >= off) ? sc[tid - off] : 0u;
            __syncthreads();
            sc[tid] = mine + add;
            __syncthreads();
        }
        const unsigned excl = sc[tid] - p;
        const unsigned* cntrow = cnt + (size_t)blk * nbp;
        if (i0 < nb) basesh[i0] = excl + cntrow[i0];
        if (i1 < nb) basesh[i1] = excl + v0 + cntrow[i1];
    }
    __syncthreads();

    unsigned rw[B2_EPT];  // packed record (u << 8) | (c & 255)
    int rb[B2_EPT];       // bucket (or -1 invalid)
    unsigned rr[B2_EPT];  // rank within (block, bucket)

    if (ecount == B2_CHUNK) {
        const int4* c4 = (const int4*)(c + estart);
        const int4* u4 = (const int4*)(u + estart);
#pragma unroll
        for (int jj = 0; jj < 4; ++jj) {
            const int k = jj * 256 + tid;
            const int4 cv = c4[k];
            const int4 uv = u4[k];
            const int j = jj * 4;
            rb[j + 0] = cv.x >> NPB_SHIFT;
            rb[j + 1] = cv.y >> NPB_SHIFT;
            rb[j + 2] = cv.z >> NPB_SHIFT;
            rb[j + 3] = cv.w >> NPB_SHIFT;
            rw[j + 0] = ((unsigned)uv.x << NPB_SHIFT) | (unsigned)(cv.x & (NPB - 1));
            rw[j + 1] = ((unsigned)uv.y << NPB_SHIFT) | (unsigned)(cv.y & (NPB - 1));
            rw[j + 2] = ((unsigned)uv.z << NPB_SHIFT) | (unsigned)(cv.z & (NPB - 1));
            rw[j + 3] = ((unsigned)uv.w << NPB_SHIFT) | (unsigned)(cv.w & (NPB - 1));
            rr[j + 0] = atomicAdd(&rank[rb[j + 0]], 1u);
            rr[j + 1] = atomicAdd(&rank[rb[j + 1]], 1u);
            rr[j + 2] = atomicAdd(&rank[rb[j + 2]], 1u);
            rr[j + 3] = atomicAdd(&rank[rb[j + 3]], 1u);
        }
    } else {
#pragma unroll
        for (int j = 0; j < B2_EPT; ++j) {
            rb[j] = -1;
            const int e = estart + j * 256 + tid;
            if (e < num_edges) {
                const int cc = c[e];
                const int uu = u[e];
                rb[j] = cc >> NPB_SHIFT;
                rw[j] = ((unsigned)uu << NPB_SHIFT) | (unsigned)(cc & (NPB - 1));
                rr[j] = atomicAdd(&rank[rb[j]], 1u);
            }
        }
    }
    __syncthreads();

    // block-local exclusive scan of rank[0..MAX_NBP) -> lstart (2 bins/thread)
    {
        const int b2 = tid * 2;
        const unsigned v0 = rank[b2 + 0];
        const unsigned v1 = rank[b2 + 1];
        const unsigned tsum = v0 + v1;
        unsigned incl = tsum;
        const int lane = tid & 63;
#pragma unroll
        for (int off = 1; off < 64; off <<= 1) {
            const unsigned nv = __shfl_up(incl, off, 64);
            if (lane >= off) incl += nv;
        }
        if (lane == 63) wtot[tid >> 6] = incl;
        __syncthreads();
        unsigned woff = 0;
        const int w = tid >> 6;
        for (int i = 0; i < w; ++i) woff += wtot[i];
        const unsigned run = woff + incl - tsum;
        lstart[b2 + 0] = run;
        lstart[b2 + 1] = run + v0;
    }
    __syncthreads();

    // scatter into LDS in bucket-major order
#pragma unroll
    for (int j = 0; j < B2_EPT; ++j) {
        if (rb[j] >= 0) {
            const unsigned pos = lstart[rb[j]] + rr[j];
            srec[pos] = rw[j];
            sbuk[pos] = (unsigned short)rb[j];
        }
    }
    __syncthreads();

    // coalesced write-out: run-contiguous in both LDS and global
    for (int i = tid; i < ecount; i += 256) {
        const int b = sbuk[i];
        recs[basesh[b] + (unsigned)i - lstart[b]] = srec[i];
    }
}

// Dot-reduce v4: one block per (bucket, chunk); no-barrier main loop with
// 2-way unroll (r9). NEW: bin_base computed locally (scan kernel gone), and
// the node pass is FUSED via the split-K last-block pattern: after flushing
// acc, each block fences + bumps bucket_done[B]; the last of the CPB chunks
// re-reads the bucket's node sums coherently (atomicAdd(p,0)) and does
// log + per-graph segment-sum inline.
__global__ __launch_bounds__(256) void pe_dotred_kernel(
    const unsigned* __restrict__ Qq,
    const unsigned* __restrict__ Kq,
    const unsigned* __restrict__ recs,
    const unsigned* __restrict__ bin_cnt,
    float* __restrict__ node_sum,
    const int* __restrict__ batch,
    float* __restrict__ out,
    unsigned* __restrict__ bucket_done,
    int num_nodes, int nb) {
    __shared__ uint4 qlds[NPB * 4];    // 16 KB: row-major, 4 uint4 per row
    __shared__ float acc[NPB];         // 1 KB
    __shared__ unsigned sc[256];       // 1 KB scan scratch
    __shared__ unsigned sbase[MAX_NBP + 1];
    __shared__ unsigned lastflag;

    const int g = blockIdx.x;
    const int B = g >> 2;
    const int chunk = g & 3;

    const int t = threadIdx.x;
    const int gteam = t >> 2;          // team 0..63
    const int sub = t & 3;
    const float inv_scale = 0.125f;    // 1/sqrt(64)

    // stage this bucket's Q rows (contiguous, coalesced)
    const int nrows = min(NPB, num_nodes - B * NPB);
    const uint4* qsrc = (const uint4*)Qq + (size_t)B * NPB * 4;
    for (int i = t; i < nrows * 4; i += 256) qlds[i] = qsrc[i];
    acc[t] = 0.0f;

    // local exclusive scan of bin_cnt -> sbase[0..nb]
    {
        const int i0 = 2 * t, i1 = 2 * t + 1;
        const unsigned v0 = (i0 < nb) ? bin_cnt[i0] : 0u;
        const unsigned v1 = (i1 < nb) ? bin_cnt[i1] : 0u;
        const unsigned p = v0 + v1;
        sc[t] = p;
        __syncthreads();
        for (int off = 1; off < 256; off <<= 1) {
            const unsigned mine = sc[t];
            const unsigned add = (t >= off) ? sc[t - off] : 0u;
            __syncthreads();
            sc[t] = mine + add;
            __syncthreads();
        }
        const unsigned excl = sc[t] - p;
        sbase[i0] = excl;
        sbase[i1] = excl + v0;
        if (t == 255) sbase[512] = sc[255];
    }
    __syncthreads();   // qlds + acc + sbase ready

    const unsigned s0 = sbase[B];
    const unsigned len = sbase[B + 1] - s0;
    const unsigned r0 = s0 + (unsigned)(((unsigned long long)len * chunk) / CPB);
    const unsigned r1 = s0 + (unsigned)(((unsigned long long)len * (chunk + 1)) / CPB);

    unsigned i = r0 + gteam;
    for (; i + 64 < r1; i += 128) {
        const unsigned recA = recs[i];
        const unsigned recB = recs[i + 64];
        const unsigned uA = recA >> NPB_SHIFT, lA = recA & (NPB - 1);
        const unsigned uB = recB >> NPB_SHIFT, lB = recB & (NPB - 1);
        const uint4 kA = *(const uint4*)(Kq + (size_t)uA * 16 + sub * 4);
        const uint4 kB = *(const uint4*)(Kq + (size_t)uB * 16 + sub * 4);
        const uint4 qA = qlds[lA * 4 + sub];
        const uint4 qB = qlds[lB * 4 + sub];
        const float dA = red4(dot16_fp8(qA, kA));
        const float dB = red4(dot16_fp8(qB, kB));
        if (sub == 0) {
            atomicAdd(&acc[lA], __expf(dA * inv_scale));
            atomicAdd(&acc[lB], __expf(dB * inv_scale));
        }
    }
    for (; i < r1; i += 64) {
        const unsigned rec = recs[i];
        const unsigned uu = rec >> NPB_SHIFT, ll = rec & (NPB - 1);
        const uint4 k = *(const uint4*)(Kq + (size_t)uu * 16 + sub * 4);
        const uint4 q4 = qlds[ll * 4 + sub];
        const float d = red4(dot16_fp8(q4, k));
        if (sub == 0) atomicAdd(&acc[ll], __expf(d * inv_scale));
    }
    __syncthreads();

    // flush partial sums
    if (t < nrows && acc[t] != 0.0f)
        atomicAdd(&node_sum[B * NPB + t], acc[t]);
    __threadfence();   // each thread: make its atomic visible device-wide
    __syncthreads();   // all fences done before the counter bump

    if (t == 0)
        lastflag = (atomicAdd(&bucket_done[B], 1u) == CPB - 1) ? 1u : 0u;
    __syncthreads();

    if (lastflag) {
        // finalize this bucket: coherent read-back + log + per-graph sum
        const int node = B * NPB + t;
        const bool valid = t < nrows;
        float s = 0.0f;
        if (valid) s = atomicAdd(&node_sum[node], 0.0f);  // far-point read
        float lse = (valid && s > 0.0f) ? logf(s) : 0.0f;
        const int nc = valid ? node : (num_nodes - 1);
        const int b = batch[nc];

        const int b0 = __shfl(b, 0, 64);
        const bool uniform = __all(b == b0);
        if (uniform) {
            lse += __shfl_xor(lse, 1, 64);
            lse += __shfl_xor(lse, 2, 64);
            lse += __shfl_xor(lse, 4, 64);
            lse += __shfl_xor(lse, 8, 64);
            lse += __shfl_xor(lse, 16, 64);
            lse += __shfl_xor(lse, 32, 64);
            if ((t & 63) == 0 && lse != 0.0f) atomicAdd(&out[b0], lse);
        } else {
            if (valid && lse != 0.0f) atomicAdd(&out[b], lse);
        }
    }
}

// Node pass (FALLBACK PATH ONLY)
__global__ __launch_bounds__(256) void pe_node_kernel(
    const float* __restrict__ node_sum,
    const int* __restrict__ batch,
    float* __restrict__ out,
    int num_nodes) {
    const int n = blockIdx.x * blockDim.x + threadIdx.x;
    const bool valid = (n < num_nodes);
    const int nc = valid ? n : (num_nodes - 1);

    const float s = valid ? node_sum[nc] : 0.0f;
    float lse = (s > 0.0f) ? logf(s) : 0.0f;
    if (!valid) lse = 0.0f;
    const int b = batch[nc];

    const int b0 = __shfl(b, 0, 64);
    const bool uniform = __all(b == b0);
    if (uniform) {
        lse += __shfl_xor(lse, 1, 64);
        lse += __shfl_xor(lse, 2, 64);
        lse += __shfl_xor(lse, 4, 64);
        lse += __shfl_xor(lse, 8, 64);
        lse += __shfl_xor(lse, 16, 64);
        lse += __shfl_xor(lse, 32, 64);
        if ((threadIdx.x & 63) == 0 && lse != 0.0f) {
            atomicAdd(&out[b0], lse);
        }
    } else {
        if (valid && lse != 0.0f) {
            atomicAdd(&out[b], lse);
        }
    }
}

// ---------- fallback path (round-0 kernels, proven correct) ----------

__global__ __launch_bounds__(256) void pe_convert_kernel(
    const float* __restrict__ Q,
    const float* __restrict__ K,
    unsigned* __restrict__ Qq,
    unsigned* __restrict__ Kq,
    float* __restrict__ node_sum,
    float* __restrict__ out,
    int n4, int num_nodes, int num_graphs) {
    const int i = blockIdx.x * blockDim.x + threadIdx.x;
    if (i < num_nodes) node_sum[i] = 0.0f;
    if (i < num_graphs) out[i] = 0.0f;
    if (i >= n4) return;
    const float4 q = ((const float4*)Q)[i];
    const float4 k = ((const float4*)K)[i];
    Qq[i] = pack4_fp8(q.x, q.y, q.z, q.w);
    Kq[i] = pack4_fp8(k.x, k.y, k.z, k.w);
}

__global__ __launch_bounds__(256) void pe_edge_kernel(
    const unsigned* __restrict__ Qq,
    const unsigned* __restrict__ Kq,
    const int* __restrict__ c,
    const int* __restrict__ u,
    float* __restrict__ node_sum,
    int num_edges) {
    const int tid = blockIdx.x * blockDim.x + threadIdx.x;
    const int group = tid >> 2;
    const int sub = tid & 3;
    const int ngroups = (gridDim.x * blockDim.x) >> 2;
    const float inv_scale = 0.125f;

    const int E4 = num_edges & ~3;

    for (int base = group * 4; base < E4; base += ngroups * 4) {
        const int4 ci = *(const int4*)(c + base);
        const int4 ui = *(const int4*)(u + base);

        const uint4 q0 = *(const uint4*)(Qq + (size_t)ci.x * 16 + sub * 4);
        const uint4 q1 = *(const uint4*)(Qq + (size_t)ci.y * 16 + sub * 4);
        const uint4 q2 = *(const uint4*)(Qq + (size_t)ci.z * 16 + sub * 4);
        const uint4 q3 = *(const uint4*)(Qq + (size_t)ci.w * 16 + sub * 4);
        const uint4 k0 = *(const uint4*)(Kq + (size_t)ui.x * 16 + sub * 4);
        const uint4 k1 = *(const uint4*)(Kq + (size_t)ui.y * 16 + sub * 4);
        const uint4 k2 = *(const uint4*)(Kq + (size_t)ui.z * 16 + sub * 4);
        const uint4 k3 = *(const uint4*)(Kq + (size_t)ui.w * 16 + sub * 4);

        float d0 = red4(dot16_fp8(q0, k0));
        float d1 = red4(dot16_fp8(q1, k1));
        float d2 = red4(dot16_fp8(q2, k2));
        float d3 = red4(dot16_fp8(q3, k3));

        const float dsel = (sub == 0) ? d0 : (sub == 1) ? d1 : (sub == 2) ? d2 : d3;
        const int csel = (sub == 0) ? ci.x : (sub == 1) ? ci.y : (sub == 2) ? ci.z : ci.w;
        atomicAdd(&node_sum[csel], __expf(dsel * inv_scale));
    }

    for (int e = E4 + group; e < num_edges; e += ngroups) {
        const int cc = c[e];
        const int uu = u[e];
        const uint4 q = *(const uint4*)(Qq + (size_t)cc * 16 + sub * 4);
        const uint4 k = *(const uint4*)(Kq + (size_t)uu * 16 + sub * 4);
        float d = red4(dot16_fp8(q, k));
        if (sub == 0) atomicAdd(&node_sum[cc], __expf(d * inv_scale));
    }
}

extern "C" void kernel_launch(void* const* d_in, const int* in_sizes, int n_in,
                              void* d_out, int out_size, void* d_ws, size_t ws_size,
                              hipStream_t stream) {
    const float* Q2 = (const float*)d_in[0];
    const float* K2 = (const float*)d_in[1];
    const int* c_2 = (const int*)d_in[2];
    const int* u_2 = (const int*)d_in[3];
    const int* batch = (const int*)d_in[4];

    const int num_nodes = in_sizes[4];
    const int num_edges = in_sizes[2];
    const int num_graphs = out_size;
    const int d = in_sizes[0] / num_nodes;   // 64
    const size_t row_elems = (size_t)num_nodes * d;
    const size_t row_bytes = row_elems;      // fp8: 1 B per element

    const int nb = (num_nodes + NPB - 1) >> NPB_SHIFT;
    const int nbp = (nb + 15) & ~15;         // pad to 16 for matscan tiles
    const int nblk = (num_edges + B2_CHUNK - 1) / B2_CHUNK;

    // ws layout (binned): Qq | Kq | meta (bin_cnt MAX_NBP, bucket_done
    //   MAX_NBP, pad) | node_sum (ns_pad f32) | recs (E u32) |
    //   cnt ([nblk][nbp] u32)
    // fallback: Qq | Kq | node_sum (at meta)
    unsigned* Qq = (unsigned*)d_ws;
    unsigned* Kq = Qq + row_bytes / 4;
    unsigned* meta = Kq + row_bytes / 4;
    unsigned* bin_cnt = meta;
    unsigned* bucket_done = meta + MAX_NBP;
    float* node_sum_b = (float*)(meta + 2 * MAX_NBP + 16);
    const size_t ns_pad = ((size_t)num_nodes + 15) & ~(size_t)15;
    unsigned* recs = (unsigned*)node_sum_b + ns_pad;
    unsigned* cnt = recs + num_edges;
    float* node_sum_f = (float*)meta;        // fallback location
    float* out = (float*)d_out;

    const size_t need_binned = row_bytes * 2 + (size_t)(2 * MAX_NBP + 16) * 4 +
                               ns_pad * 4 + (size_t)num_edges * 4 +
                               (size_t)nblk * nbp * 4;
    const bool use_binned = (nb <= MAX_NBP) && (ws_size >= need_binned) &&
                            (d == 64) && (num_nodes <= (1 << 23));

    float* node_sum = use_binned ? node_sum_b : node_sum_f;
    const int n4 = (int)(row_elems / 4);
    const int nconv = (n4 + 255) / 256;

    if (use_binned) {
        // merged count (first) + convert; zero node_sum/out/bucket_done
        pe_convcount_kernel<<<nblk + nconv, 256, 0, stream>>>(
            Q2, K2, Qq, Kq, node_sum, out, bucket_done, c_2, cnt,
            n4, num_nodes, num_graphs, num_edges, nbp, nblk);
        // per-bin exclusive scan over blocks (16-bin column tiles)
        pe_matscan_kernel<<<nbp / 16, 256, 0, stream>>>(cnt, bin_cnt,
                                                        nblk, nbp);
        pe_binify_kernel<<<nblk, 256, 0, stream>>>(c_2, u_2, cnt,
                                                   bin_cnt, recs,
                                                   num_edges, nb, nbp, nblk);
        // dot + reduce + fused node/graph finalize (last chunk per bucket)
        pe_dotred_kernel<<<nb * CPB, 256, 0, stream>>>(
            Qq, Kq, recs, bin_cnt, node_sum, batch, out, bucket_done,
            num_nodes, nb);
    } else {
        pe_convert_kernel<<<nconv, 256, 0, stream>>>(
            Q2, K2, Qq, Kq, node_sum, out, n4, num_nodes, num_graphs);
        pe_edge_kernel<<<8192, 256, 0, stream>>>(Qq, Kq, c_2, u_2,
                                                 node_sum, num_edges);
        const int grid = (num_nodes + 255) / 256;
        pe_node_kernel<<<grid, 256, 0, stream>>>(node_sum, batch, out,
                                                 num_nodes);
    }
}

// Round 11
// 198.900 us; speedup vs baseline: 1.6668x; 1.6668x over previous
//
#include <hip/hip_runtime.h>
#include <hip/hip_fp8.h>
#include <math.h>

typedef __attribute__((ext_vector_type(2))) float fv2;

#if defined(__has_builtin)
#  if __has_builtin(__builtin_amdgcn_cvt_pk_f32_fp8) && \
      __has_builtin(__builtin_amdgcn_cvt_pk_fp8_f32)
#    define PE_HAVE_FP8_BUILTINS 1
#  endif
#endif

#define MAX_NBP 512          // max c-buckets for binned path
#define NPB 256              // nodes per bucket
#define NPB_SHIFT 8
#define B2_EPT 16            // edges per thread in count/binify
#define B2_CHUNK (B2_EPT * 256)   // 4096 edges per block
#define CPB 4                // chunks per bucket in dotred

// pack 4 floats -> 4 fp8 e4m3 bytes in one uint32
__device__ __forceinline__ unsigned pack4_fp8(float a, float b, float c, float d) {
#ifdef PE_HAVE_FP8_BUILTINS
    int w = 0;
    w = __builtin_amdgcn_cvt_pk_fp8_f32(a, b, w, false);  // bytes 0,1
    w = __builtin_amdgcn_cvt_pk_fp8_f32(c, d, w, true);   // bytes 2,3
    return (unsigned)w;
#else
    unsigned r = 0;
    r |= (unsigned)__hip_fp8_e4m3(a).__x;
    r |= (unsigned)__hip_fp8_e4m3(b).__x << 8;
    r |= (unsigned)__hip_fp8_e4m3(c).__x << 16;
    r |= (unsigned)__hip_fp8_e4m3(d).__x << 24;
    return r;
#endif
}

__device__ __forceinline__ float dot4w_fp8(unsigned qa, unsigned ka, float acc) {
#ifdef PE_HAVE_FP8_BUILTINS
    fv2 q0 = __builtin_amdgcn_cvt_pk_f32_fp8((int)qa, false);
    fv2 q1 = __builtin_amdgcn_cvt_pk_f32_fp8((int)qa, true);
    fv2 k0 = __builtin_amdgcn_cvt_pk_f32_fp8((int)ka, false);
    fv2 k1 = __builtin_amdgcn_cvt_pk_f32_fp8((int)ka, true);
    acc = fmaf(q0.x, k0.x, acc);
    acc = fmaf(q0.y, k0.y, acc);
    acc = fmaf(q1.x, k1.x, acc);
    acc = fmaf(q1.y, k1.y, acc);
    return acc;
#else
#pragma unroll
    for (int j = 0; j < 4; ++j) {
        __hip_fp8_e4m3 qv, kv;
        qv.__x = (qa >> (8 * j)) & 0xff;
        kv.__x = (ka >> (8 * j)) & 0xff;
        acc = fmaf((float)qv, (float)kv, acc);
    }
    return acc;
#endif
}

__device__ __forceinline__ float dot16_fp8(const uint4& q, const uint4& k) {
    float d = 0.0f;
    d = dot4w_fp8(q.x, k.x, d);
    d = dot4w_fp8(q.y, k.y, d);
    d = dot4w_fp8(q.z, k.z, d);
    d = dot4w_fp8(q.w, k.w, d);
    return d;
}

__device__ __forceinline__ float red4(float d) {
    d += __shfl_xor(d, 1, 64);
    d += __shfl_xor(d, 2, 64);
    return d;
}

// Pass 0 (merged): blocks [0, nblk) do the per-chunk bucket histogram
// (dispatched FIRST: slower blocks start earliest, smaller makespan);
// blocks [nblk, nblk+nconv) do fp32->fp8 conversion + zeroing.
// cnt layout is [blk][bin] (row stride nbp) -> coalesced row writes.
__global__ __launch_bounds__(256) void pe_convcount_kernel(
    const float* __restrict__ Q,
    const float* __restrict__ K,
    unsigned* __restrict__ Qq,   // row = 16 uints = 64 fp8
    unsigned* __restrict__ Kq,
    float* __restrict__ node_sum,
    float* __restrict__ out,
    const int* __restrict__ c,
    unsigned* __restrict__ cnt,       // [nblk][nbp]
    int n4, int num_nodes, int num_graphs, int num_edges,
    int nbp, int nblk) {
    __shared__ unsigned h[MAX_NBP];
    const int tid = threadIdx.x;

    if (blockIdx.x >= nblk) {
        const int i = (blockIdx.x - nblk) * 256 + tid;
        if (i < num_nodes) node_sum[i] = 0.0f;
        if (i < num_graphs) out[i] = 0.0f;
        if (i >= n4) return;
        const float4 q = ((const float4*)Q)[i];
        const float4 k = ((const float4*)K)[i];
        Qq[i] = pack4_fp8(q.x, q.y, q.z, q.w);
        Kq[i] = pack4_fp8(k.x, k.y, k.z, k.w);
        return;
    }

    // ---- count branch ----
    const int blk = blockIdx.x;
    for (int b = tid; b < MAX_NBP; b += 256) h[b] = 0u;
    __syncthreads();

    const int estart = blk * B2_CHUNK;
    const int ecount = min(B2_CHUNK, num_edges - estart);
    const int n4e = ecount >> 2;
    const int4* c4 = (const int4*)(c + estart);
    for (int k = tid; k < n4e; k += 256) {
        const int4 v = c4[k];
        atomicAdd(&h[v.x >> NPB_SHIFT], 1u);
        atomicAdd(&h[v.y >> NPB_SHIFT], 1u);
        atomicAdd(&h[v.z >> NPB_SHIFT], 1u);
        atomicAdd(&h[v.w >> NPB_SHIFT], 1u);
    }
    for (int e = (n4e << 2) + tid; e < ecount; e += 256)
        atomicAdd(&h[c[estart + e] >> NPB_SHIFT], 1u);
    __syncthreads();

    // coalesced row write (includes zero pad columns)
    for (int b = tid; b < nbp; b += 256)
        cnt[(size_t)blk * nbp + b] = h[b];
}

// Per-bin exclusive scan over blocks, cnt layout [blk][bin], in place.
// One block per 16-bin tile; each thread consumes a FULL 64B line (16 u32).
__global__ __launch_bounds__(256) void pe_matscan_kernel(
    unsigned* __restrict__ cnt,       // [nblk][nbp]
    unsigned* __restrict__ bin_cnt,
    int nblk, int nbp) {
    __shared__ unsigned wsum[4][16];
    const int t = threadIdx.x;
    const int lane = t & 63;
    const int w = t >> 6;
    const int col0 = blockIdx.x * 16;

    unsigned carry[16];
#pragma unroll
    for (int i = 0; i < 16; ++i) carry[i] = 0u;

    for (int t0 = 0; t0 < nblk; t0 += 256) {
        const int blk = t0 + t;
        unsigned v[16], orig[16];
        if (blk < nblk) {
            const uint4* p = (const uint4*)(cnt + (size_t)blk * nbp + col0);
            const uint4 a = p[0], b = p[1], cc = p[2], dd = p[3];
            v[0]=a.x;  v[1]=a.y;  v[2]=a.z;  v[3]=a.w;
            v[4]=b.x;  v[5]=b.y;  v[6]=b.z;  v[7]=b.w;
            v[8]=cc.x; v[9]=cc.y; v[10]=cc.z; v[11]=cc.w;
            v[12]=dd.x; v[13]=dd.y; v[14]=dd.z; v[15]=dd.w;
        } else {
#pragma unroll
            for (int i = 0; i < 16; ++i) v[i] = 0u;
        }
#pragma unroll
        for (int i = 0; i < 16; ++i) orig[i] = v[i];

        // wave-level inclusive scan (vector of 16)
#pragma unroll
        for (int off = 1; off < 64; off <<= 1) {
            unsigned nv[16];
#pragma unroll
            for (int i = 0; i < 16; ++i) nv[i] = __shfl_up(v[i], off, 64);
            if (lane >= off) {
#pragma unroll
                for (int i = 0; i < 16; ++i) v[i] += nv[i];
            }
        }
        if (lane == 63) {
#pragma unroll
            for (int i = 0; i < 16; ++i) wsum[w][i] = v[i];
        }
        __syncthreads();

        unsigned woff[16];
#pragma unroll
        for (int i = 0; i < 16; ++i) woff[i] = 0u;
        for (int ww = 0; ww < w; ++ww)
#pragma unroll
            for (int i = 0; i < 16; ++i) woff[i] += wsum[ww][i];

        if (blk < nblk) {
            uint4 o[4];
            unsigned e[16];
#pragma unroll
            for (int i = 0; i < 16; ++i) e[i] = carry[i] + woff[i] + v[i] - orig[i];
            o[0] = make_uint4(e[0], e[1], e[2], e[3]);
            o[1] = make_uint4(e[4], e[5], e[6], e[7]);
            o[2] = make_uint4(e[8], e[9], e[10], e[11]);
            o[3] = make_uint4(e[12], e[13], e[14], e[15]);
            uint4* p = (uint4*)(cnt + (size_t)blk * nbp + col0);
            p[0] = o[0]; p[1] = o[1]; p[2] = o[2]; p[3] = o[3];
        }

#pragma unroll
        for (int i = 0; i < 16; ++i)
            carry[i] += wsum[0][i] + wsum[1][i] + wsum[2][i] + wsum[3][i];
        __syncthreads();   // protect wsum before next iteration
    }

    if (t == 0) {
#pragma unroll
        for (int i = 0; i < 16; ++i) bin_cnt[col0 + i] = carry[i];
    }
}

// Binify: deterministic scatter with LDS reorder (coarse buckets).
// The global bin_base is computed LOCALLY (256-wide pair scan of bin_cnt,
// ~1.5 KB read, free) -- no standalone scan kernel.
__global__ __launch_bounds__(256) void pe_binify_kernel(
    const int* __restrict__ c,
    const int* __restrict__ u,
    const unsigned* __restrict__ cnt,        // scanned, [nblk][nbp]
    const unsigned* __restrict__ bin_cnt,
    unsigned* __restrict__ recs,
    int num_edges, int nb, int nbp, int nblk) {
    __shared__ unsigned rank[MAX_NBP];        // 2 KB
    __shared__ unsigned lstart[MAX_NBP];      // 2 KB
    __shared__ unsigned basesh[MAX_NBP];      // 2 KB
    __shared__ unsigned srec[B2_CHUNK];       // 16 KB reordered records
    __shared__ unsigned short sbuk[B2_CHUNK]; // 8 KB bucket per slot
    __shared__ unsigned sc[256];              // 1 KB scan scratch
    __shared__ unsigned wtot[4];

    const int tid = threadIdx.x;
    const int blk = blockIdx.x;
    const int estart = blk * B2_CHUNK;
    const int ecount = min(B2_CHUNK, num_edges - estart);

    for (int b = tid; b < MAX_NBP; b += 256) rank[b] = 0u;

    // local exclusive scan of bin_cnt -> per-block global bases
    {
        const int i0 = 2 * tid, i1 = 2 * tid + 1;
        const unsigned v0 = (i0 < nb) ? bin_cnt[i0] : 0u;
        const unsigned v1 = (i1 < nb) ? bin_cnt[i1] : 0u;
        const unsigned p = v0 + v1;
        sc[tid] = p;
        __syncthreads();
        for (int off = 1; off < 256; off <<= 1) {
            const unsigned mine = sc[tid];
            const unsigned add = (tid >= off) ? sc[tid - off] : 0u;
            __syncthreads();
            sc[tid] = mine + add;
            __syncthreads();
        }
        const unsigned excl = sc[tid] - p;
        const unsigned* cntrow = cnt + (size_t)blk * nbp;
        if (i0 < nb) basesh[i0] = excl + cntrow[i0];
        if (i1 < nb) basesh[i1] = excl + v0 + cntrow[i1];
    }
    __syncthreads();

    unsigned rw[B2_EPT];  // packed record (u << 8) | (c & 255)
    int rb[B2_EPT];       // bucket (or -1 invalid)
    unsigned rr[B2_EPT];  // rank within (block, bucket)

    if (ecount == B2_CHUNK) {
        const int4* c4 = (const int4*)(c + estart);
        const int4* u4 = (const int4*)(u + estart);
#pragma unroll
        for (int jj = 0; jj < 4; ++jj) {
            const int k = jj * 256 + tid;
            const int4 cv = c4[k];
            const int4 uv = u4[k];
            const int j = jj * 4;
            rb[j + 0] = cv.x >> NPB_SHIFT;
            rb[j + 1] = cv.y >> NPB_SHIFT;
            rb[j + 2] = cv.z >> NPB_SHIFT;
            rb[j + 3] = cv.w >> NPB_SHIFT;
            rw[j + 0] = ((unsigned)uv.x << NPB_SHIFT) | (unsigned)(cv.x & (NPB - 1));
            rw[j + 1] = ((unsigned)uv.y << NPB_SHIFT) | (unsigned)(cv.y & (NPB - 1));
            rw[j + 2] = ((unsigned)uv.z << NPB_SHIFT) | (unsigned)(cv.z & (NPB - 1));
            rw[j + 3] = ((unsigned)uv.w << NPB_SHIFT) | (unsigned)(cv.w & (NPB - 1));
            rr[j + 0] = atomicAdd(&rank[rb[j + 0]], 1u);
            rr[j + 1] = atomicAdd(&rank[rb[j + 1]], 1u);
            rr[j + 2] = atomicAdd(&rank[rb[j + 2]], 1u);
            rr[j + 3] = atomicAdd(&rank[rb[j + 3]], 1u);
        }
    } else {
#pragma unroll
        for (int j = 0; j < B2_EPT; ++j) {
            rb[j] = -1;
            const int e = estart + j * 256 + tid;
            if (e < num_edges) {
                const int cc = c[e];
                const int uu = u[e];
                rb[j] = cc >> NPB_SHIFT;
                rw[j] = ((unsigned)uu << NPB_SHIFT) | (unsigned)(cc & (NPB - 1));
                rr[j] = atomicAdd(&rank[rb[j]], 1u);
            }
        }
    }
    __syncthreads();

    // block-local exclusive scan of rank[0..MAX_NBP) -> lstart (2 bins/thread)
    {
        const int b2 = tid * 2;
        const unsigned v0 = rank[b2 + 0];
        const unsigned v1 = rank[b2 + 1];
        const unsigned tsum = v0 + v1;
        unsigned incl = tsum;
        const int lane = tid & 63;
#pragma unroll
        for (int off = 1; off < 64; off <<= 1) {
            const unsigned nv = __shfl_up(incl, off, 64);
            if (lane >= off) incl += nv;
        }
        if (lane == 63) wtot[tid >> 6] = incl;
        __syncthreads();
        unsigned woff = 0;
        const int w = tid >> 6;
        for (int i = 0; i < w; ++i) woff += wtot[i];
        const unsigned run = woff + incl - tsum;
        lstart[b2 + 0] = run;
        lstart[b2 + 1] = run + v0;
    }
    __syncthreads();

    // scatter into LDS in bucket-major order
#pragma unroll
    for (int j = 0; j < B2_EPT; ++j) {
        if (rb[j] >= 0) {
            const unsigned pos = lstart[rb[j]] + rr[j];
            srec[pos] = rw[j];
            sbuk[pos] = (unsigned short)rb[j];
        }
    }
    __syncthreads();

    // coalesced write-out: run-contiguous in both LDS and global
    for (int i = tid; i < ecount; i += 256) {
        const int b = sbuk[i];
        recs[basesh[b] + (unsigned)i - lstart[b]] = srec[i];
    }
}

// Dot-reduce (r9 structure — proven 41 us, the measured random-line wall):
// one block per (bucket, chunk); no barriers in the main loop; 2-way
// unroll (two independent gather+dot chains per team). bin_base computed
// locally. NO fence / NO in-kernel finalize: r10 showed per-block
// __threadfence() on non-coherent-L2 CDNA4 costs 5x the kernel (the
// kernel boundary is the cheap device-wide fence).
__global__ __launch_bounds__(256) void pe_dotred_kernel(
    const unsigned* __restrict__ Qq,
    const unsigned* __restrict__ Kq,
    const unsigned* __restrict__ recs,
    const unsigned* __restrict__ bin_cnt,
    float* __restrict__ node_sum,
    int num_nodes, int nb) {
    __shared__ uint4 qlds[NPB * 4];    // 16 KB: row-major, 4 uint4 per row
    __shared__ float acc[NPB];         // 1 KB
    __shared__ unsigned sc[256];       // 1 KB scan scratch
    __shared__ unsigned sbase[MAX_NBP + 1];

    const int g = blockIdx.x;
    const int B = g >> 2;
    const int chunk = g & 3;
    if (B >= nb) return;

    const int t = threadIdx.x;
    const int gteam = t >> 2;          // team 0..63
    const int sub = t & 3;
    const float inv_scale = 0.125f;    // 1/sqrt(64)

    // stage this bucket's Q rows (contiguous, coalesced)
    const int nrows = min(NPB, num_nodes - B * NPB);
    const uint4* qsrc = (const uint4*)Qq + (size_t)B * NPB * 4;
    for (int i = t; i < nrows * 4; i += 256) qlds[i] = qsrc[i];
    acc[t] = 0.0f;

    // local exclusive scan of bin_cnt -> sbase[B], sbase[B+1]
    {
        const int i0 = 2 * t, i1 = 2 * t + 1;
        const unsigned v0 = (i0 < nb) ? bin_cnt[i0] : 0u;
        const unsigned v1 = (i1 < nb) ? bin_cnt[i1] : 0u;
        const unsigned p = v0 + v1;
        sc[t] = p;
        __syncthreads();
        for (int off = 1; off < 256; off <<= 1) {
            const unsigned mine = sc[t];
            const unsigned add = (t >= off) ? sc[t - off] : 0u;
            __syncthreads();
            sc[t] = mine + add;
            __syncthreads();
        }
        const unsigned excl = sc[t] - p;
        sbase[i0] = excl;
        sbase[i1] = excl + v0;
        if (t == 255) sbase[512] = sc[255];
    }
    __syncthreads();   // qlds + acc + sbase ready

    const unsigned s0 = sbase[B];
    const unsigned len = sbase[B + 1] - s0;
    const unsigned r0 = s0 + (unsigned)(((unsigned long long)len * chunk) / CPB);
    const unsigned r1 = s0 + (unsigned)(((unsigned long long)len * (chunk + 1)) / CPB);

    unsigned i = r0 + gteam;
    for (; i + 64 < r1; i += 128) {
        const unsigned recA = recs[i];
        const unsigned recB = recs[i + 64];
        const unsigned uA = recA >> NPB_SHIFT, lA = recA & (NPB - 1);
        const unsigned uB = recB >> NPB_SHIFT, lB = recB & (NPB - 1);
        const uint4 kA = *(const uint4*)(Kq + (size_t)uA * 16 + sub * 4);
        const uint4 kB = *(const uint4*)(Kq + (size_t)uB * 16 + sub * 4);
        const uint4 qA = qlds[lA * 4 + sub];
        const uint4 qB = qlds[lB * 4 + sub];
        const float dA = red4(dot16_fp8(qA, kA));
        const float dB = red4(dot16_fp8(qB, kB));
        if (sub == 0) {
            atomicAdd(&acc[lA], __expf(dA * inv_scale));
            atomicAdd(&acc[lB], __expf(dB * inv_scale));
        }
    }
    for (; i < r1; i += 64) {
        const unsigned rec = recs[i];
        const unsigned uu = rec >> NPB_SHIFT, ll = rec & (NPB - 1);
        const uint4 k = *(const uint4*)(Kq + (size_t)uu * 16 + sub * 4);
        const uint4 q4 = qlds[ll * 4 + sub];
        const float d = red4(dot16_fp8(q4, k));
        if (sub == 0) atomicAdd(&acc[ll], __expf(d * inv_scale));
    }
    __syncthreads();

    if (t < nrows && acc[t] != 0.0f)
        atomicAdd(&node_sum[B * NPB + t], acc[t]);
}

// Node pass: lse = log(node_sum[n]) (0 for empty), segment-sum into out.
__global__ __launch_bounds__(256) void pe_node_kernel(
    const float* __restrict__ node_sum,
    const int* __restrict__ batch,
    float* __restrict__ out,
    int num_nodes) {
    const int n = blockIdx.x * blockDim.x + threadIdx.x;
    const bool valid = (n < num_nodes);
    const int nc = valid ? n : (num_nodes - 1);

    const float s = valid ? node_sum[nc] : 0.0f;
    float lse = (s > 0.0f) ? logf(s) : 0.0f;
    if (!valid) lse = 0.0f;
    const int b = batch[nc];

    const int b0 = __shfl(b, 0, 64);
    const bool uniform = __all(b == b0);
    if (uniform) {
        lse += __shfl_xor(lse, 1, 64);
        lse += __shfl_xor(lse, 2, 64);
        lse += __shfl_xor(lse, 4, 64);
        lse += __shfl_xor(lse, 8, 64);
        lse += __shfl_xor(lse, 16, 64);
        lse += __shfl_xor(lse, 32, 64);
        if ((threadIdx.x & 63) == 0 && lse != 0.0f) {
            atomicAdd(&out[b0], lse);
        }
    } else {
        if (valid && lse != 0.0f) {
            atomicAdd(&out[b], lse);
        }
    }
}

// ---------- fallback path (round-0 kernels, proven correct) ----------

__global__ __launch_bounds__(256) void pe_convert_kernel(
    const float* __restrict__ Q,
    const float* __restrict__ K,
    unsigned* __restrict__ Qq,
    unsigned* __restrict__ Kq,
    float* __restrict__ node_sum,
    float* __restrict__ out,
    int n4, int num_nodes, int num_graphs) {
    const int i = blockIdx.x * blockDim.x + threadIdx.x;
    if (i < num_nodes) node_sum[i] = 0.0f;
    if (i < num_graphs) out[i] = 0.0f;
    if (i >= n4) return;
    const float4 q = ((const float4*)Q)[i];
    const float4 k = ((const float4*)K)[i];
    Qq[i] = pack4_fp8(q.x, q.y, q.z, q.w);
    Kq[i] = pack4_fp8(k.x, k.y, k.z, k.w);
}

__global__ __launch_bounds__(256) void pe_edge_kernel(
    const unsigned* __restrict__ Qq,
    const unsigned* __restrict__ Kq,
    const int* __restrict__ c,
    const int* __restrict__ u,
    float* __restrict__ node_sum,
    int num_edges) {
    const int tid = blockIdx.x * blockDim.x + threadIdx.x;
    const int group = tid >> 2;
    const int sub = tid & 3;
    const int ngroups = (gridDim.x * blockDim.x) >> 2;
    const float inv_scale = 0.125f;

    const int E4 = num_edges & ~3;

    for (int base = group * 4; base < E4; base += ngroups * 4) {
        const int4 ci = *(const int4*)(c + base);
        const int4 ui = *(const int4*)(u + base);

        const uint4 q0 = *(const uint4*)(Qq + (size_t)ci.x * 16 + sub * 4);
        const uint4 q1 = *(const uint4*)(Qq + (size_t)ci.y * 16 + sub * 4);
        const uint4 q2 = *(const uint4*)(Qq + (size_t)ci.z * 16 + sub * 4);
        const uint4 q3 = *(const uint4*)(Qq + (size_t)ci.w * 16 + sub * 4);
        const uint4 k0 = *(const uint4*)(Kq + (size_t)ui.x * 16 + sub * 4);
        const uint4 k1 = *(const uint4*)(Kq + (size_t)ui.y * 16 + sub * 4);
        const uint4 k2 = *(const uint4*)(Kq + (size_t)ui.z * 16 + sub * 4);
        const uint4 k3 = *(const uint4*)(Kq + (size_t)ui.w * 16 + sub * 4);

        float d0 = red4(dot16_fp8(q0, k0));
        float d1 = red4(dot16_fp8(q1, k1));
        float d2 = red4(dot16_fp8(q2, k2));
        float d3 = red4(dot16_fp8(q3, k3));

        const float dsel = (sub == 0) ? d0 : (sub == 1) ? d1 : (sub == 2) ? d2 : d3;
        const int csel = (sub == 0) ? ci.x : (sub == 1) ? ci.y : (sub == 2) ? ci.z : ci.w;
        atomicAdd(&node_sum[csel], __expf(dsel * inv_scale));
    }

    for (int e = E4 + group; e < num_edges; e += ngroups) {
        const int cc = c[e];
        const int uu = u[e];
        const uint4 q = *(const uint4*)(Qq + (size_t)cc * 16 + sub * 4);
        const uint4 k = *(const uint4*)(Kq + (size_t)uu * 16 + sub * 4);
        float d = red4(dot16_fp8(q, k));
        if (sub == 0) atomicAdd(&node_sum[cc], __expf(d * inv_scale));
    }
}

extern "C" void kernel_launch(void* const* d_in, const int* in_sizes, int n_in,
                              void* d_out, int out_size, void* d_ws, size_t ws_size,
                              hipStream_t stream) {
    const float* Q2 = (const float*)d_in[0];
    const float* K2 = (const float*)d_in[1];
    const int* c_2 = (const int*)d_in[2];
    const int* u_2 = (const int*)d_in[3];
    const int* batch = (const int*)d_in[4];

    const int num_nodes = in_sizes[4];
    const int num_edges = in_sizes[2];
    const int num_graphs = out_size;
    const int d = in_sizes[0] / num_nodes;   // 64
    const size_t row_elems = (size_t)num_nodes * d;
    const size_t row_bytes = row_elems;      // fp8: 1 B per element

    const int nb = (num_nodes + NPB - 1) >> NPB_SHIFT;
    const int nbp = (nb + 15) & ~15;         // pad to 16 for matscan tiles
    const int nblk = (num_edges + B2_CHUNK - 1) / B2_CHUNK;

    // ws layout (binned): Qq | Kq | meta (bin_cnt MAX_NBP, pad) |
    //   node_sum (ns_pad f32) | recs (E u32) | cnt ([nblk][nbp] u32)
    // fallback: Qq | Kq | node_sum (at meta)
    unsigned* Qq = (unsigned*)d_ws;
    unsigned* Kq = Qq + row_bytes / 4;
    unsigned* meta = Kq + row_bytes / 4;
    unsigned* bin_cnt = meta;
    float* node_sum_b = (float*)(meta + MAX_NBP + 16);
    const size_t ns_pad = ((size_t)num_nodes + 15) & ~(size_t)15;
    unsigned* recs = (unsigned*)node_sum_b + ns_pad;
    unsigned* cnt = recs + num_edges;
    float* node_sum_f = (float*)meta;        // fallback location
    float* out = (float*)d_out;

    const size_t need_binned = row_bytes * 2 + (size_t)(MAX_NBP + 16) * 4 +
                               ns_pad * 4 + (size_t)num_edges * 4 +
                               (size_t)nblk * nbp * 4;
    const bool use_binned = (nb <= MAX_NBP) && (ws_size >= need_binned) &&
                            (d == 64) && (num_nodes <= (1 << 23));

    float* node_sum = use_binned ? node_sum_b : node_sum_f;
    const int n4 = (int)(row_elems / 4);
    const int nconv = (n4 + 255) / 256;

    if (use_binned) {
        // merged count (first) + convert (zeroes node_sum/out)
        pe_convcount_kernel<<<nblk + nconv, 256, 0, stream>>>(
            Q2, K2, Qq, Kq, node_sum, out, c_2, cnt,
            n4, num_nodes, num_graphs, num_edges, nbp, nblk);
        // per-bin exclusive scan over blocks (16-bin column tiles)
        pe_matscan_kernel<<<nbp / 16, 256, 0, stream>>>(cnt, bin_cnt,
                                                        nblk, nbp);
        pe_binify_kernel<<<nblk, 256, 0, stream>>>(c_2, u_2, cnt,
                                                   bin_cnt, recs,
                                                   num_edges, nb, nbp, nblk);
        pe_dotred_kernel<<<nb * CPB, 256, 0, stream>>>(
            Qq, Kq, recs, bin_cnt, node_sum, num_nodes, nb);
        const int grid = (num_nodes + 255) / 256;
        pe_node_kernel<<<grid, 256, 0, stream>>>(node_sum, batch, out,
                                                 num_nodes);
    } else {
        pe_convert_kernel<<<nconv, 256, 0, stream>>>(
            Q2, K2, Qq, Kq, node_sum, out, n4, num_nodes, num_graphs);
        pe_edge_kernel<<<8192, 256, 0, stream>>>(Qq, Kq, c_2, u_2,
                                                 node_sum, num_edges);
        const int grid = (num_nodes + 255) / 256;
        pe_node_kernel<<<grid, 256, 0, stream>>>(node_sum, batch, out,
                                                 num_nodes);
    }
}